// Round 12
// baseline (857.290 us; speedup 1.0000x reference)
//
#include <hip/hip_runtime.h>
#include <math.h>

#define HID 128
#define NLAYERS 4
#define NGRAPHS 200
#define NCLASSES 10
#define BN_EPS 1e-5f

typedef short bf16x8 __attribute__((ext_vector_type(8)));
typedef float f32x4 __attribute__((ext_vector_type(4)));

__device__ __forceinline__ ushort f2bf(float f) {
    unsigned u = __float_as_uint(f);
    u = (u + 0x7fffu + ((u >> 16) & 1u)) >> 16;
    return (ushort)u;
}
__device__ __forceinline__ float bf2f(unsigned us) { return __uint_as_float(us << 16); }

// ---------------- prep kernels ----------------

// A[:,128:256] = bf16(x)  (h state lives only in A's h-half, bf16)
__global__ void k_init_x(const float* __restrict__ x, ushort* __restrict__ A, int N) {
    int idx = blockIdx.x * blockDim.x + threadIdx.x;
    if (idx < N * HID) {
        int n = idx >> 7, c = idx & 127;
        A[n * 256 + 128 + c] = f2bf(x[idx]);
    }
}

// C[l][k][j] = sum_o W_l[k][o] * w_ih[j][o]   (fp32, composed message+input weights)
__global__ __launch_bounds__(128) void k_wgemm(const float* __restrict__ W,
                                               const float* __restrict__ w_ih,
                                               float* __restrict__ C) {
    int l = blockIdx.x >> 7, k = blockIdx.x & 127;
    __shared__ float wrow[128];
    wrow[threadIdx.x] = W[(l << 14) + k * 128 + threadIdx.x];
    __syncthreads();
    for (int j = threadIdx.x; j < 384; j += 128) {
        float acc = 0.f;
#pragma unroll 4
        for (int o = 0; o < 128; ++o) acc += wrow[o] * w_ih[j * 128 + o];
        C[((size_t)l * 128 + k) * 384 + j] = acc;
    }
}

// Per-layer combined GRU weights in MFMA-fragment order (K=256 over [s|h], 512 outs)
__global__ void k_build_Bc(const float* __restrict__ C, const float* __restrict__ w_hh,
                           ushort* __restrict__ Bc2) {
    int idx = blockIdx.x * blockDim.x + threadIdx.x;
    if (idx >= NLAYERS * 512 * 256) return;
    int jf = idx & 7, lane = (idx >> 3) & 63, ks = (idx >> 9) & 7, ct = (idx >> 12) & 31;
    int l = idx >> 17;
    int o = ct * 16 + (lane & 15);
    int k = ks * 32 + (lane >> 4) * 8 + jf;
    float v;
    if (k < 128)      v = (o < 384) ? C[((size_t)l * 128 + k) * 384 + o] : 0.f;
    else if (o < 256) v = w_hh[o * 128 + (k - 128)];
    else if (o < 384) v = 0.f;
    else              v = w_hh[(o - 128) * 128 + (k - 128)];
    Bc2[idx] = f2bf(v);
}

__global__ void k_bias(const float* __restrict__ b_ih, const float* __restrict__ b_hh,
                       float* __restrict__ bias) {
    int j = threadIdx.x;
    if (j >= 512) return;
    float v;
    if (j < 256)      v = b_ih[j] + b_hh[j];
    else if (j < 384) v = b_ih[j];
    else              v = b_hh[j - 128];
    bias[j] = v;
}

// fc1_w[o][k] -> fragment order (K=128: ks in [0,4), ct in [0,8))
__global__ void k_cvt_fc1(const float* __restrict__ w, ushort* __restrict__ B2) {
    int idx = blockIdx.x * blockDim.x + threadIdx.x;
    if (idx >= 16384) return;
    int j = idx & 7, lane = (idx >> 3) & 63, ks = (idx >> 9) & 3, ct = idx >> 11;
    int o = ct * 16 + (lane & 15);
    int k = ks * 32 + (lane >> 4) * 8 + j;
    B2[idx] = f2bf(w[o * 128 + k]);
}

// ---------------- CSR build: staged counting-sort (no write amplification) ----------
// R10 lesson: NO dynamically-indexed register arrays (-> scratch). Scatter pass
// re-reads the chunk from global (L1/L2-hot after the hist pass).

#define CHUNK 2048

// blocks [0,nchunk): per-chunk bucket histogram; blocks [nchunk, ...): gstart
__global__ __launch_bounds__(256) void k_bhist(const int* __restrict__ ei, int E,
                                               int nb, int* __restrict__ bhist,
                                               const int* __restrict__ batch,
                                               int* __restrict__ gstart, int N,
                                               int nchunk) {
    if ((int)blockIdx.x < nchunk) {
        __shared__ int lh[256];
        int t = threadIdx.x;
        lh[t] = 0;
        __syncthreads();
        int base = blockIdx.x * CHUNK;
        int end = min(base + CHUNK, E);
        for (int i = base + t; i < end; i += 256) atomicAdd(&lh[ei[E + i] >> 9], 1);
        __syncthreads();
        if (t < nb && lh[t]) atomicAdd(&bhist[t], lh[t]);
    } else {
        int n = (blockIdx.x - nchunk) * 256 + threadIdx.x;
        if (n > N) return;
        int curb = (n == N) ? NGRAPHS : batch[n];
        int prev = (n == 0) ? -1 : batch[n - 1];
        for (int g = prev + 1; g <= curb; ++g) gstart[g] = n;
    }
}

__global__ void k_bscan(const int* __restrict__ bhist, int nb, int* __restrict__ bstart,
                        int* __restrict__ bcur, int E) {
    __shared__ int s[256];
    int t = threadIdx.x;
    int v = (t < nb) ? bhist[t] : 0;
    s[t] = v;
    __syncthreads();
    for (int off = 1; off < 256; off <<= 1) {
        int a = (t >= off) ? s[t - off] : 0;
        __syncthreads();
        s[t] += a;
        __syncthreads();
    }
    if (t < nb) { int ex = s[t] - v; bstart[t] = ex; bcur[t] = ex; }
    if (t == 0) bstart[nb] = E;
}

__global__ __launch_bounds__(256) void k_binfill(const int* __restrict__ ei, int E,
                                                 int nb, int* __restrict__ bcur,
                                                 int2* __restrict__ binned) {
    __shared__ int eh[256], eoff[256], ecur[256], gbase[256];
    __shared__ int2 sbuf[CHUNK];
    int t = threadIdx.x;
    eh[t] = 0; ecur[t] = 0;
    __syncthreads();
    int base = blockIdx.x * CHUNK;
    int cnt = min(CHUNK, E - base);
    for (int i = t; i < cnt; i += 256) atomicAdd(&eh[ei[E + base + i] >> 9], 1);
    __syncthreads();
    int v = eh[t];
    eoff[t] = v;
    __syncthreads();
    for (int off = 1; off < 256; off <<= 1) {
        int a = (t >= off) ? eoff[t - off] : 0;
        __syncthreads();
        eoff[t] += a;
        __syncthreads();
    }
    int excl = eoff[t] - v;
    __syncthreads();
    eoff[t] = excl;
    __syncthreads();
    for (int i = t; i < cnt; i += 256) {
        int s = ei[base + i], d = ei[E + base + i];
        int b = d >> 9;
        int slot = eoff[b] + atomicAdd(&ecur[b], 1);
        sbuf[slot] = make_int2(s, d);
    }
    __syncthreads();
    if (t < nb && eh[t]) gbase[t] = atomicAdd(&bcur[t], eh[t]);
    __syncthreads();
    for (int i = t; i < cnt; i += 256) {
        int2 e = sbuf[i];
        int b = e.y >> 9;
        binned[gbase[b] + (i - eoff[b])] = e;
    }
}

__global__ __launch_bounds__(256) void k_csr512(const int2* __restrict__ binned,
                                                const int* __restrict__ bstart,
                                                int* __restrict__ rowstart,
                                                int* __restrict__ col, int N, int E) {
    __shared__ int h[512], cur[512], sc[512];
    int t = threadIdx.x, b = blockIdx.x;
    int es = bstart[b], ee = bstart[b + 1];
    for (int i = t; i < 512; i += 256) h[i] = 0;
    __syncthreads();
    for (int i = es + t; i < ee; i += 256) atomicAdd(&h[binned[i].y & 511], 1);
    __syncthreads();
    for (int i = t; i < 512; i += 256) sc[i] = h[i];
    __syncthreads();
    for (int off = 1; off < 512; off <<= 1) {
        int i0 = t, i1 = t + 256;
        int a0 = (i0 >= off) ? sc[i0 - off] : 0;
        int a1 = (i1 >= off) ? sc[i1 - off] : 0;
        __syncthreads();
        sc[i0] += a0; sc[i1] += a1;
        __syncthreads();
    }
    for (int i = t; i < 512; i += 256) {
        int excl = sc[i] - h[i];
        cur[i] = excl;
        int node = (b << 9) + i;
        if (node < N) rowstart[node] = es + excl;
    }
    __syncthreads();
    for (int i = es + t; i < ee; i += 256) {
        int2 e = binned[i];
        int p = atomicAdd(&cur[e.y & 511], 1);
        col[es + p] = e.x;
    }
    if (b == 0 && t == 0) rowstart[N] = E;
}

// ---------------- CSR gather: A[:,0:128] = sum over in-edges of A[src,128:256] --------
// High-occupancy standalone kernel, 8 rows in flight per slot for MLP; col reads
// are nontemporal (streaming, read-once) to keep L2 for the A rows.

__global__ __launch_bounds__(256) void k_gather_bf(const int* __restrict__ rowstart,
                                                   const int* __restrict__ col,
                                                   ushort* __restrict__ A, int N) {
    int node = blockIdx.x * 4 + (threadIdx.x >> 6);
    int lane = threadIdx.x & 63;
    if (node >= N) return;
    int s = rowstart[node], e = rowstart[node + 1];
    int sub = lane >> 4;   // edge slot 0..3
    int chunk = lane & 15; // 16B chunk in row
    const ushort* hb = A + 128; // h-half, stride 256
    float acc[8];
#pragma unroll
    for (int k = 0; k < 8; ++k) acc[k] = 0.f;
    int i = s + sub;
    for (; i + 28 < e; i += 32) {
        int c0 = __builtin_nontemporal_load(col + i);
        int c1 = __builtin_nontemporal_load(col + i + 4);
        int c2 = __builtin_nontemporal_load(col + i + 8);
        int c3 = __builtin_nontemporal_load(col + i + 12);
        int c4 = __builtin_nontemporal_load(col + i + 16);
        int c5 = __builtin_nontemporal_load(col + i + 20);
        int c6 = __builtin_nontemporal_load(col + i + 24);
        int c7 = __builtin_nontemporal_load(col + i + 28);
        bf16x8 v0 = *(const bf16x8*)(hb + (size_t)c0 * 256 + chunk * 8);
        bf16x8 v1 = *(const bf16x8*)(hb + (size_t)c1 * 256 + chunk * 8);
        bf16x8 v2 = *(const bf16x8*)(hb + (size_t)c2 * 256 + chunk * 8);
        bf16x8 v3 = *(const bf16x8*)(hb + (size_t)c3 * 256 + chunk * 8);
        bf16x8 v4 = *(const bf16x8*)(hb + (size_t)c4 * 256 + chunk * 8);
        bf16x8 v5 = *(const bf16x8*)(hb + (size_t)c5 * 256 + chunk * 8);
        bf16x8 v6 = *(const bf16x8*)(hb + (size_t)c6 * 256 + chunk * 8);
        bf16x8 v7 = *(const bf16x8*)(hb + (size_t)c7 * 256 + chunk * 8);
#pragma unroll
        for (int k = 0; k < 8; ++k) {
            acc[k] += bf2f((ushort)v0[k]) + bf2f((ushort)v1[k]);
            acc[k] += bf2f((ushort)v2[k]) + bf2f((ushort)v3[k]);
            acc[k] += bf2f((ushort)v4[k]) + bf2f((ushort)v5[k]);
            acc[k] += bf2f((ushort)v6[k]) + bf2f((ushort)v7[k]);
        }
    }
    for (; i < e; i += 4) {
        int c0 = col[i];
        bf16x8 v0 = *(const bf16x8*)(hb + (size_t)c0 * 256 + chunk * 8);
#pragma unroll
        for (int k = 0; k < 8; ++k) acc[k] += bf2f((ushort)v0[k]);
    }
#pragma unroll
    for (int k = 0; k < 8; ++k) {
        acc[k] += __shfl_xor(acc[k], 16);
        acc[k] += __shfl_xor(acc[k], 32);
    }
    if (sub == 0) {
        union { ushort u[8]; bf16x8 v; } o;
#pragma unroll
        for (int k = 0; k < 8; ++k) o.u[k] = f2bf(acc[k]);
        *(bf16x8*)(A + (size_t)node * 256 + chunk * 8) = o.v;
    }
}

// ---------------- fused GRU GEMM (K=256 over [s|h]); h state bf16-only --------------
// NOTE: min-waves MUST stay 2 — at 4 the allocator caps VGPR at 64 and spills the
// 128-reg accumulator array to scratch (R8: 1.3 GB HBM traffic, 274 us).

#define LDA 264
__global__ __launch_bounds__(256, 2) void k_gru_mfma(
    const ushort* __restrict__ A, const ushort* __restrict__ Bc2,
    const float* __restrict__ bias, ushort* __restrict__ Ah) {
    __shared__ ushort As[64 * LDA];
    int t = threadIdx.x;
    int rowb = blockIdx.x << 6;
    for (int c = t; c < 2048; c += 256) {
        int r = c >> 5, off = (c & 31) * 8;
        *(bf16x8*)(As + r * LDA + off) =
            *(const bf16x8*)(A + (size_t)(rowb + r) * 256 + off);
    }
    __syncthreads();
    int w = t >> 6, lane = t & 63;
    int quad = lane >> 4, tn = lane & 15;
    f32x4 acc[4][4][2];
#pragma unroll
    for (int rt = 0; rt < 4; ++rt)
#pragma unroll
        for (int g = 0; g < 4; ++g)
#pragma unroll
            for (int c2 = 0; c2 < 2; ++c2) acc[rt][g][c2] = (f32x4){0.f, 0.f, 0.f, 0.f};
    for (int ks = 0; ks < 8; ++ks) {
        int k0 = ks * 32 + quad * 8;
        bf16x8 bfr[4][2];
#pragma unroll
        for (int g = 0; g < 4; ++g)
#pragma unroll
            for (int c2 = 0; c2 < 2; ++c2) {
                int ct = g * 8 + w * 2 + c2;
                bfr[g][c2] = *(const bf16x8*)(Bc2 + (size_t)((ct * 8 + ks) * 64 + lane) * 8);
            }
        bf16x8 af[4];
#pragma unroll
        for (int rt = 0; rt < 4; ++rt)
            af[rt] = *(const bf16x8*)(As + (rt * 16 + tn) * LDA + k0);
#pragma unroll
        for (int rt = 0; rt < 4; ++rt)
#pragma unroll
            for (int g = 0; g < 4; ++g)
#pragma unroll
                for (int c2 = 0; c2 < 2; ++c2)
                    acc[rt][g][c2] = __builtin_amdgcn_mfma_f32_16x16x32_bf16(
                        af[rt], bfr[g][c2], acc[rt][g][c2], 0, 0, 0);
    }
#pragma unroll
    for (int c2 = 0; c2 < 2; ++c2) {
        int cc = w * 32 + c2 * 16 + tn;
        float br = bias[cc], bz = bias[128 + cc], bin = bias[256 + cc], bhn = bias[384 + cc];
#pragma unroll
        for (int rt = 0; rt < 4; ++rt)
#pragma unroll
            for (int r = 0; r < 4; ++r) {
                int rl = rt * 16 + quad * 4 + r;
                int row = rowb + rl;
                float ur = acc[rt][0][c2][r] + br;
                float uz = acc[rt][1][c2][r] + bz;
                float xin = acc[rt][2][c2][r] + bin;
                float xhn = acc[rt][3][c2][r] + bhn;
                float rr = 1.f / (1.f + __expf(-ur));
                float zz = 1.f / (1.f + __expf(-uz));
                float xt = xin + rr * xhn;
                float ex = __expf(2.f * fminf(fmaxf(xt, -15.f), 15.f));
                float nn = (ex - 1.f) / (ex + 1.f);
                float ho = bf2f(As[rl * LDA + 128 + cc]);
                float hv = (1.f - zz) * nn + zz * ho;
                Ah[(size_t)row * 256 + cc] = f2bf(hv);
            }
    }
}

// ---------------- MFMA GEMM (fc1) with fused BN-stats ----------
// Per-thread: 16 y-values per col (c2); quad-reduce (shfl 16/32), 2 atomics/col
// into 64-sliced statsl (~25 hits/slot — no contention). Rows >= N masked.

#define LDA2 136
__global__ __launch_bounds__(256, 2) void k_mm_mfma(
    const ushort* __restrict__ Ain, int astride, const ushort* __restrict__ B2,
    ushort* __restrict__ mo, float* __restrict__ statsl, int N) {
    __shared__ ushort As[64 * LDA2];
    int t = threadIdx.x;
    int rowb = blockIdx.x << 6;
    for (int c = t; c < 1024; c += 256) {
        int r = c >> 4, off = (c & 15) * 8;
        *(bf16x8*)(As + r * LDA2 + off) =
            *(const bf16x8*)(Ain + (size_t)(rowb + r) * astride + off);
    }
    __syncthreads();
    int w = t >> 6, lane = t & 63;
    int quad = lane >> 4, tn = lane & 15;
    f32x4 acc[4][2];
#pragma unroll
    for (int rt = 0; rt < 4; ++rt)
#pragma unroll
        for (int c2 = 0; c2 < 2; ++c2) acc[rt][c2] = (f32x4){0.f, 0.f, 0.f, 0.f};
    for (int ks = 0; ks < 4; ++ks) {
        int k0 = ks * 32 + quad * 8;
        bf16x8 bfr[2];
#pragma unroll
        for (int c2 = 0; c2 < 2; ++c2) {
            int ct = w * 2 + c2;
            bfr[c2] = *(const bf16x8*)(B2 + (size_t)((ct * 4 + ks) * 64 + lane) * 8);
        }
        bf16x8 af[4];
#pragma unroll
        for (int rt = 0; rt < 4; ++rt)
            af[rt] = *(const bf16x8*)(As + (rt * 16 + tn) * LDA2 + k0);
#pragma unroll
        for (int rt = 0; rt < 4; ++rt)
#pragma unroll
            for (int c2 = 0; c2 < 2; ++c2)
                acc[rt][c2] = __builtin_amdgcn_mfma_f32_16x16x32_bf16(
                    af[rt], bfr[c2], acc[rt][c2], 0, 0, 0);
    }
#pragma unroll
    for (int c2 = 0; c2 < 2; ++c2) {
        int col = w * 32 + c2 * 16 + tn;
        float s = 0.f, s2 = 0.f;
#pragma unroll
        for (int rt = 0; rt < 4; ++rt)
#pragma unroll
            for (int r = 0; r < 4; ++r) {
                int row = rowb + rt * 16 + quad * 4 + r;
                float v = acc[rt][c2][r];
                mo[row * 128 + col] = f2bf(v);
                if (row < N) { s += v; s2 += v * v; }
            }
        s += __shfl_xor(s, 16);
        s += __shfl_xor(s, 32);
        s2 += __shfl_xor(s2, 16);
        s2 += __shfl_xor(s2, 32);
        if (quad == 0) {
            int slice = blockIdx.x & 63;
            atomicAdd(&statsl[(slice * 2 + 0) * 128 + col], s);
            atomicAdd(&statsl[(slice * 2 + 1) * 128 + col], s2);
        }
    }
}

// ---------------- BN finalize / pool / head ----------------

__global__ void k_bnfinal(const float* __restrict__ statsl, float* __restrict__ stats,
                          const float* __restrict__ gamma,
                          const float* __restrict__ beta, float n) {
    int j = threadIdx.x;
    if (j < HID) {
        float s = 0.f, s2 = 0.f;
        for (int sl = 0; sl < 64; ++sl) {
            s += statsl[(sl * 2 + 0) * 128 + j];
            s2 += statsl[(sl * 2 + 1) * 128 + j];
        }
        float mu = s / n;
        float var = s2 / n - mu * mu;
        float sc = gamma[j] * rsqrtf(var + BN_EPS);
        stats[256 + j] = sc;
        stats[384 + j] = beta[j] - mu * sc;
    }
}

// atomic-light pool: block = (graph, quarter), rows contiguous via gstart
__global__ __launch_bounds__(256) void k_pool(const ushort* __restrict__ y,
                                              const float* __restrict__ stats,
                                              const int* __restrict__ gstart,
                                              float* __restrict__ gsum) {
    int g = blockIdx.x >> 2, q = blockIdx.x & 3;
    int f = threadIdx.x & 127, half = threadIdx.x >> 7;
    int gs = gstart[g], ge = gstart[g + 1];
    int len = ge - gs;
    int r0 = gs + ((len * q) >> 2), r1 = gs + ((len * (q + 1)) >> 2);
    float sc = stats[256 + f], sh = stats[384 + f];
    float acc = 0.f;
    for (int n = r0 + half; n < r1; n += 2)
        acc += fmaxf(bf2f(y[n * HID + f]) * sc + sh, 0.f);
    __shared__ float ls[2][HID];
    ls[half][f] = acc;
    __syncthreads();
    if (half == 0) atomicAdd(&gsum[g * HID + f], ls[0][f] + ls[1][f]);
}

__global__ void k_head(const float* __restrict__ gsum, const int* __restrict__ gstart,
                       const float* __restrict__ w2, const float* __restrict__ b2,
                       float* __restrict__ out) {
    int g = blockIdx.x * blockDim.x + threadIdx.x;
    if (g >= NGRAPHS) return;
    float cnt = (float)(gstart[g + 1] - gstart[g]);
    float inv = 1.0f / fmaxf(cnt, 1.0f);
    float logits[NCLASSES];
    float mx = -1e30f;
    for (int c = 0; c < NCLASSES; ++c) {
        float acc = b2[c];
        for (int f = 0; f < HID; ++f) acc += gsum[g * HID + f] * inv * w2[c * HID + f];
        logits[c] = acc;
        mx = fmaxf(mx, acc);
    }
    float se = 0.f;
    for (int c = 0; c < NCLASSES; ++c) se += expf(logits[c] - mx);
    float lse = mx + logf(se);
    for (int c = 0; c < NCLASSES; ++c) out[g * NCLASSES + c] = logits[c] - lse;
}

// ---------------- launch ----------------

extern "C" void kernel_launch(void* const* d_in, const int* in_sizes, int n_in,
                              void* d_out, int out_size, void* d_ws, size_t ws_size,
                              hipStream_t stream) {
    const float* x     = (const float*)d_in[0];
    const int*   ei    = (const int*)d_in[1];
    const int*   batch = (const int*)d_in[2];
    const float* ggnnw = (const float*)d_in[3];
    const float* w_ih  = (const float*)d_in[4];
    const float* w_hh  = (const float*)d_in[5];
    const float* b_ih  = (const float*)d_in[6];
    const float* b_hh  = (const float*)d_in[7];
    const float* fc1_w = (const float*)d_in[8];
    // d_in[9] fc1_b: cancels exactly in training-mode BN -> unused
    const float* gamma = (const float*)d_in[10];
    const float* beta  = (const float*)d_in[11];
    const float* fc2_w = (const float*)d_in[12];
    const float* fc2_b = (const float*)d_in[13];
    float* out = (float*)d_out;

    const int N = in_sizes[0] / HID; // 100000
    const int E = in_sizes[1] / 2;   // 1600000
    const int nblk64 = (N + 63) / 64;
    const int P = nblk64 * 64;
    const int nbuck = (N + 511) >> 9; // 196

    char* w = (char*)d_ws;
    auto alloc = [&](size_t bytes) -> char* {
        char* p = w;
        w += (bytes + 255) & ~(size_t)255;
        return p;
    };
    ushort* A   = (ushort*)alloc(sizeof(ushort) * (size_t)P * 256); // [s | h] bf16
    ushort* y   = (ushort*)alloc(sizeof(ushort) * (size_t)P * HID); // fc1 output
    int2*   binned = (int2*)y; // alias: binned dead before k_mm writes y
    ushort* Bc2 = (ushort*)alloc(sizeof(ushort) * NLAYERS * 512 * 256);
    float*  C   = (float*)alloc(sizeof(float) * NLAYERS * 128 * 384);
    ushort* f1b = (ushort*)alloc(sizeof(ushort) * HID * HID);
    float*  bias = (float*)alloc(sizeof(float) * 512);
    int* rowstart = (int*)alloc(sizeof(int) * (N + 4));
    int* colb     = (int*)alloc(sizeof(int) * E);
    int* bstart   = (int*)alloc(sizeof(int) * (nbuck + 4));
    int* bcur     = (int*)alloc(sizeof(int) * (nbuck + 4));
    int* gstart   = (int*)alloc(sizeof(int) * (NGRAPHS + 4));
    // zero-initialized region: bhist, statsl (64 slices x 2 x 128), stats, gsum
    size_t zelems = (size_t)nbuck + 64 * 2 * 128 + 512 + NGRAPHS * HID;
    char* zbase = alloc(zelems * 4);
    int*   bhist  = (int*)zbase;
    float* statsl = (float*)(bhist + nbuck);
    float* stats  = statsl + 64 * 2 * 128;
    float* gsum   = stats + 512;

    hipMemsetAsync(zbase, 0, zelems * 4, stream);

    k_init_x<<<(N * HID + 255) / 256, 256, 0, stream>>>(x, A, N);
    k_wgemm<<<NLAYERS * 128, 128, 0, stream>>>(ggnnw, w_ih, C);
    k_build_Bc<<<(NLAYERS * 512 * 256 + 255) / 256, 256, 0, stream>>>(C, w_hh, Bc2);
    k_bias<<<1, 512, 0, stream>>>(b_ih, b_hh, bias);
    k_cvt_fc1<<<(16384 + 255) / 256, 256, 0, stream>>>(fc1_w, f1b);

    // staged CSR build (+ gstart fused into bhist dispatch)
    int nchunk = (E + CHUNK - 1) / CHUNK;
    int ngblk = (N + 256) / 256;
    k_bhist<<<nchunk + ngblk, 256, 0, stream>>>(ei, E, nbuck, bhist, batch, gstart, N,
                                                nchunk);
    k_bscan<<<1, 256, 0, stream>>>(bhist, nbuck, bstart, bcur, E);
    k_binfill<<<nchunk, 256, 0, stream>>>(ei, E, nbuck, bcur, binned);
    k_csr512<<<nbuck, 256, 0, stream>>>(binned, bstart, rowstart, colb, N, E);

    for (int l = 0; l < NLAYERS; ++l) {
        k_gather_bf<<<(N + 3) / 4, 256, 0, stream>>>(rowstart, colb, A, N);
        k_gru_mfma<<<nblk64, 256, 0, stream>>>(A, Bc2 + (size_t)l * 512 * 256,
                                               bias, A + 128);
    }

    // head: fc1 (+fused BN stats) -> BN finalize -> pool -> fc2 -> log_softmax
    k_mm_mfma<<<nblk64, 256, 0, stream>>>(A + 128, 256, f1b, y, statsl, N);
    k_bnfinal<<<1, 128, 0, stream>>>(statsl, stats, gamma, beta, (float)N);
    k_pool<<<NGRAPHS * 4, 256, 0, stream>>>(y, stats, gstart, gsum);
    k_head<<<1, 256, 0, stream>>>(gsum, gstart, fc2_w, fc2_b, out);
}

// Round 13
// 739.594 us; speedup vs baseline: 1.1591x; 1.1591x over previous
//
#include <hip/hip_runtime.h>
#include <math.h>

#define HID 128
#define NLAYERS 4
#define NGRAPHS 200
#define NCLASSES 10
#define BN_EPS 1e-5f

typedef short bf16x8 __attribute__((ext_vector_type(8)));
typedef float f32x4 __attribute__((ext_vector_type(4)));

__device__ __forceinline__ ushort f2bf(float f) {
    unsigned u = __float_as_uint(f);
    u = (u + 0x7fffu + ((u >> 16) & 1u)) >> 16;
    return (ushort)u;
}
__device__ __forceinline__ float bf2f(unsigned us) { return __uint_as_float(us << 16); }

// ---------------- prep kernels ----------------

// A[:,128:256] = bf16(x)  (h state lives only in A's h-half, bf16)
__global__ void k_init_x(const float* __restrict__ x, ushort* __restrict__ A, int N) {
    int idx = blockIdx.x * blockDim.x + threadIdx.x;
    if (idx < N * HID) {
        int n = idx >> 7, c = idx & 127;
        A[n * 256 + 128 + c] = f2bf(x[idx]);
    }
}

// C[l][k][j] = sum_o W_l[k][o] * w_ih[j][o]   (fp32, composed message+input weights)
__global__ __launch_bounds__(128) void k_wgemm(const float* __restrict__ W,
                                               const float* __restrict__ w_ih,
                                               float* __restrict__ C) {
    int l = blockIdx.x >> 7, k = blockIdx.x & 127;
    __shared__ float wrow[128];
    wrow[threadIdx.x] = W[(l << 14) + k * 128 + threadIdx.x];
    __syncthreads();
    for (int j = threadIdx.x; j < 384; j += 128) {
        float acc = 0.f;
#pragma unroll 4
        for (int o = 0; o < 128; ++o) acc += wrow[o] * w_ih[j * 128 + o];
        C[((size_t)l * 128 + k) * 384 + j] = acc;
    }
}

// Per-layer combined GRU weights in MFMA-fragment order (K=256 over [s|h], 512 outs)
__global__ void k_build_Bc(const float* __restrict__ C, const float* __restrict__ w_hh,
                           ushort* __restrict__ Bc2) {
    int idx = blockIdx.x * blockDim.x + threadIdx.x;
    if (idx >= NLAYERS * 512 * 256) return;
    int jf = idx & 7, lane = (idx >> 3) & 63, ks = (idx >> 9) & 7, ct = (idx >> 12) & 31;
    int l = idx >> 17;
    int o = ct * 16 + (lane & 15);
    int k = ks * 32 + (lane >> 4) * 8 + jf;
    float v;
    if (k < 128)      v = (o < 384) ? C[((size_t)l * 128 + k) * 384 + o] : 0.f;
    else if (o < 256) v = w_hh[o * 128 + (k - 128)];
    else if (o < 384) v = 0.f;
    else              v = w_hh[(o - 128) * 128 + (k - 128)];
    Bc2[idx] = f2bf(v);
}

__global__ void k_bias(const float* __restrict__ b_ih, const float* __restrict__ b_hh,
                       float* __restrict__ bias) {
    int j = threadIdx.x;
    if (j >= 512) return;
    float v;
    if (j < 256)      v = b_ih[j] + b_hh[j];
    else if (j < 384) v = b_ih[j];
    else              v = b_hh[j - 128];
    bias[j] = v;
}

// fc1_w[o][k] -> fragment order (K=128: ks in [0,4), ct in [0,8))
__global__ void k_cvt_fc1(const float* __restrict__ w, ushort* __restrict__ B2) {
    int idx = blockIdx.x * blockDim.x + threadIdx.x;
    if (idx >= 16384) return;
    int j = idx & 7, lane = (idx >> 3) & 63, ks = (idx >> 9) & 3, ct = idx >> 11;
    int o = ct * 16 + (lane & 15);
    int k = ks * 32 + (lane >> 4) * 8 + j;
    B2[idx] = f2bf(w[o * 128 + k]);
}

// ---------------- CSR build: staged counting-sort (no write amplification) ----------
// R10 lesson: NO dynamically-indexed register arrays (-> scratch). Scatter pass
// re-reads the chunk from global (L1/L2-hot after the hist pass).

#define CHUNK 2048

// blocks [0,nchunk): per-chunk bucket histogram; blocks [nchunk, ...): gstart
__global__ __launch_bounds__(256) void k_bhist(const int* __restrict__ ei, int E,
                                               int nb, int* __restrict__ bhist,
                                               const int* __restrict__ batch,
                                               int* __restrict__ gstart, int N,
                                               int nchunk) {
    if ((int)blockIdx.x < nchunk) {
        __shared__ int lh[256];
        int t = threadIdx.x;
        lh[t] = 0;
        __syncthreads();
        int base = blockIdx.x * CHUNK;
        int end = min(base + CHUNK, E);
        for (int i = base + t; i < end; i += 256) atomicAdd(&lh[ei[E + i] >> 9], 1);
        __syncthreads();
        if (t < nb && lh[t]) atomicAdd(&bhist[t], lh[t]);
    } else {
        int n = (blockIdx.x - nchunk) * 256 + threadIdx.x;
        if (n > N) return;
        int curb = (n == N) ? NGRAPHS : batch[n];
        int prev = (n == 0) ? -1 : batch[n - 1];
        for (int g = prev + 1; g <= curb; ++g) gstart[g] = n;
    }
}

__global__ void k_bscan(const int* __restrict__ bhist, int nb, int* __restrict__ bstart,
                        int* __restrict__ bcur, int E) {
    __shared__ int s[256];
    int t = threadIdx.x;
    int v = (t < nb) ? bhist[t] : 0;
    s[t] = v;
    __syncthreads();
    for (int off = 1; off < 256; off <<= 1) {
        int a = (t >= off) ? s[t - off] : 0;
        __syncthreads();
        s[t] += a;
        __syncthreads();
    }
    if (t < nb) { int ex = s[t] - v; bstart[t] = ex; bcur[t] = ex; }
    if (t == 0) bstart[nb] = E;
}

__global__ __launch_bounds__(256) void k_binfill(const int* __restrict__ ei, int E,
                                                 int nb, int* __restrict__ bcur,
                                                 int2* __restrict__ binned) {
    __shared__ int eh[256], eoff[256], ecur[256], gbase[256];
    __shared__ int2 sbuf[CHUNK];
    int t = threadIdx.x;
    eh[t] = 0; ecur[t] = 0;
    __syncthreads();
    int base = blockIdx.x * CHUNK;
    int cnt = min(CHUNK, E - base);
    for (int i = t; i < cnt; i += 256) atomicAdd(&eh[ei[E + base + i] >> 9], 1);
    __syncthreads();
    int v = eh[t];
    eoff[t] = v;
    __syncthreads();
    for (int off = 1; off < 256; off <<= 1) {
        int a = (t >= off) ? eoff[t - off] : 0;
        __syncthreads();
        eoff[t] += a;
        __syncthreads();
    }
    int excl = eoff[t] - v;
    __syncthreads();
    eoff[t] = excl;
    __syncthreads();
    for (int i = t; i < cnt; i += 256) {
        int s = ei[base + i], d = ei[E + base + i];
        int b = d >> 9;
        int slot = eoff[b] + atomicAdd(&ecur[b], 1);
        sbuf[slot] = make_int2(s, d);
    }
    __syncthreads();
    if (t < nb && eh[t]) gbase[t] = atomicAdd(&bcur[t], eh[t]);
    __syncthreads();
    for (int i = t; i < cnt; i += 256) {
        int2 e = sbuf[i];
        int b = e.y >> 9;
        binned[gbase[b] + (i - eoff[b])] = e;
    }
}

__global__ __launch_bounds__(256) void k_csr512(const int2* __restrict__ binned,
                                                const int* __restrict__ bstart,
                                                int* __restrict__ rowstart,
                                                int* __restrict__ col, int N, int E) {
    __shared__ int h[512], cur[512], sc[512];
    int t = threadIdx.x, b = blockIdx.x;
    int es = bstart[b], ee = bstart[b + 1];
    for (int i = t; i < 512; i += 256) h[i] = 0;
    __syncthreads();
    for (int i = es + t; i < ee; i += 256) atomicAdd(&h[binned[i].y & 511], 1);
    __syncthreads();
    for (int i = t; i < 512; i += 256) sc[i] = h[i];
    __syncthreads();
    for (int off = 1; off < 512; off <<= 1) {
        int i0 = t, i1 = t + 256;
        int a0 = (i0 >= off) ? sc[i0 - off] : 0;
        int a1 = (i1 >= off) ? sc[i1 - off] : 0;
        __syncthreads();
        sc[i0] += a0; sc[i1] += a1;
        __syncthreads();
    }
    for (int i = t; i < 512; i += 256) {
        int excl = sc[i] - h[i];
        cur[i] = excl;
        int node = (b << 9) + i;
        if (node < N) rowstart[node] = es + excl;
    }
    __syncthreads();
    for (int i = es + t; i < ee; i += 256) {
        int2 e = binned[i];
        int p = atomicAdd(&cur[e.y & 511], 1);
        col[es + p] = e.x;
    }
    if (b == 0 && t == 0) rowstart[N] = E;
}

// ---------------- CSR gather: A[:,0:128] = sum over in-edges of A[src,128:256] --------
// High-occupancy standalone kernel (no LDS, 28 VGPR, ~68% occupancy): TLP is the
// latency hiding here. R12 lesson: 8-deep unroll raised VGPR to 44, occupancy
// fell to 44%, 60 -> 92 us. Keep 4 rows in flight and plain loads.

__global__ __launch_bounds__(256) void k_gather_bf(const int* __restrict__ rowstart,
                                                   const int* __restrict__ col,
                                                   ushort* __restrict__ A, int N) {
    int node = blockIdx.x * 4 + (threadIdx.x >> 6);
    int lane = threadIdx.x & 63;
    if (node >= N) return;
    int s = rowstart[node], e = rowstart[node + 1];
    int sub = lane >> 4;   // edge slot 0..3
    int chunk = lane & 15; // 16B chunk in row
    const ushort* hb = A + 128; // h-half, stride 256
    float acc[8];
#pragma unroll
    for (int k = 0; k < 8; ++k) acc[k] = 0.f;
    int i = s + sub;
    for (; i + 12 < e; i += 16) {
        int c0 = col[i], c1 = col[i + 4], c2 = col[i + 8], c3 = col[i + 12];
        bf16x8 v0 = *(const bf16x8*)(hb + (size_t)c0 * 256 + chunk * 8);
        bf16x8 v1 = *(const bf16x8*)(hb + (size_t)c1 * 256 + chunk * 8);
        bf16x8 v2 = *(const bf16x8*)(hb + (size_t)c2 * 256 + chunk * 8);
        bf16x8 v3 = *(const bf16x8*)(hb + (size_t)c3 * 256 + chunk * 8);
#pragma unroll
        for (int k = 0; k < 8; ++k) {
            acc[k] += bf2f((ushort)v0[k]) + bf2f((ushort)v1[k]);
            acc[k] += bf2f((ushort)v2[k]) + bf2f((ushort)v3[k]);
        }
    }
    for (; i < e; i += 4) {
        int c0 = col[i];
        bf16x8 v0 = *(const bf16x8*)(hb + (size_t)c0 * 256 + chunk * 8);
#pragma unroll
        for (int k = 0; k < 8; ++k) acc[k] += bf2f((ushort)v0[k]);
    }
#pragma unroll
    for (int k = 0; k < 8; ++k) {
        acc[k] += __shfl_xor(acc[k], 16);
        acc[k] += __shfl_xor(acc[k], 32);
    }
    if (sub == 0) {
        union { ushort u[8]; bf16x8 v; } o;
#pragma unroll
        for (int k = 0; k < 8; ++k) o.u[k] = f2bf(acc[k]);
        *(bf16x8*)(A + (size_t)node * 256 + chunk * 8) = o.v;
    }
}

// ---------------- fused GRU GEMM (K=256 over [s|h]); h state bf16-only --------------
// NOTE: min-waves MUST stay 2 — at 4 the allocator caps VGPR at 64 and spills the
// 128-reg accumulator array to scratch (R8: 1.3 GB HBM traffic, 274 us).

#define LDA 264
__global__ __launch_bounds__(256, 2) void k_gru_mfma(
    const ushort* __restrict__ A, const ushort* __restrict__ Bc2,
    const float* __restrict__ bias, ushort* __restrict__ Ah) {
    __shared__ ushort As[64 * LDA];
    int t = threadIdx.x;
    int rowb = blockIdx.x << 6;
    for (int c = t; c < 2048; c += 256) {
        int r = c >> 5, off = (c & 31) * 8;
        *(bf16x8*)(As + r * LDA + off) =
            *(const bf16x8*)(A + (size_t)(rowb + r) * 256 + off);
    }
    __syncthreads();
    int w = t >> 6, lane = t & 63;
    int quad = lane >> 4, tn = lane & 15;
    f32x4 acc[4][4][2];
#pragma unroll
    for (int rt = 0; rt < 4; ++rt)
#pragma unroll
        for (int g = 0; g < 4; ++g)
#pragma unroll
            for (int c2 = 0; c2 < 2; ++c2) acc[rt][g][c2] = (f32x4){0.f, 0.f, 0.f, 0.f};
    for (int ks = 0; ks < 8; ++ks) {
        int k0 = ks * 32 + quad * 8;
        bf16x8 bfr[4][2];
#pragma unroll
        for (int g = 0; g < 4; ++g)
#pragma unroll
            for (int c2 = 0; c2 < 2; ++c2) {
                int ct = g * 8 + w * 2 + c2;
                bfr[g][c2] = *(const bf16x8*)(Bc2 + (size_t)((ct * 8 + ks) * 64 + lane) * 8);
            }
        bf16x8 af[4];
#pragma unroll
        for (int rt = 0; rt < 4; ++rt)
            af[rt] = *(const bf16x8*)(As + (rt * 16 + tn) * LDA + k0);
#pragma unroll
        for (int rt = 0; rt < 4; ++rt)
#pragma unroll
            for (int g = 0; g < 4; ++g)
#pragma unroll
                for (int c2 = 0; c2 < 2; ++c2)
                    acc[rt][g][c2] = __builtin_amdgcn_mfma_f32_16x16x32_bf16(
                        af[rt], bfr[g][c2], acc[rt][g][c2], 0, 0, 0);
    }
#pragma unroll
    for (int c2 = 0; c2 < 2; ++c2) {
        int cc = w * 32 + c2 * 16 + tn;
        float br = bias[cc], bz = bias[128 + cc], bin = bias[256 + cc], bhn = bias[384 + cc];
#pragma unroll
        for (int rt = 0; rt < 4; ++rt)
#pragma unroll
            for (int r = 0; r < 4; ++r) {
                int rl = rt * 16 + quad * 4 + r;
                int row = rowb + rl;
                float ur = acc[rt][0][c2][r] + br;
                float uz = acc[rt][1][c2][r] + bz;
                float xin = acc[rt][2][c2][r] + bin;
                float xhn = acc[rt][3][c2][r] + bhn;
                float rr = 1.f / (1.f + __expf(-ur));
                float zz = 1.f / (1.f + __expf(-uz));
                float xt = xin + rr * xhn;
                float ex = __expf(2.f * fminf(fmaxf(xt, -15.f), 15.f));
                float nn = (ex - 1.f) / (ex + 1.f);
                float ho = bf2f(As[rl * LDA + 128 + cc]);
                float hv = (1.f - zz) * nn + zz * ho;
                Ah[(size_t)row * 256 + cc] = f2bf(hv);
            }
    }
}

// ---------------- MFMA GEMM (fc1) with fused BN-stats ----------
// Per-thread: 16 y-values per col (c2); quad-reduce (shfl 16/32), 2 atomics/col
// into 64-sliced statsl (~25 hits/slot — no contention). Rows >= N masked.

#define LDA2 136
__global__ __launch_bounds__(256, 2) void k_mm_mfma(
    const ushort* __restrict__ Ain, int astride, const ushort* __restrict__ B2,
    ushort* __restrict__ mo, float* __restrict__ statsl, int N) {
    __shared__ ushort As[64 * LDA2];
    int t = threadIdx.x;
    int rowb = blockIdx.x << 6;
    for (int c = t; c < 1024; c += 256) {
        int r = c >> 4, off = (c & 15) * 8;
        *(bf16x8*)(As + r * LDA2 + off) =
            *(const bf16x8*)(Ain + (size_t)(rowb + r) * astride + off);
    }
    __syncthreads();
    int w = t >> 6, lane = t & 63;
    int quad = lane >> 4, tn = lane & 15;
    f32x4 acc[4][2];
#pragma unroll
    for (int rt = 0; rt < 4; ++rt)
#pragma unroll
        for (int c2 = 0; c2 < 2; ++c2) acc[rt][c2] = (f32x4){0.f, 0.f, 0.f, 0.f};
    for (int ks = 0; ks < 4; ++ks) {
        int k0 = ks * 32 + quad * 8;
        bf16x8 bfr[2];
#pragma unroll
        for (int c2 = 0; c2 < 2; ++c2) {
            int ct = w * 2 + c2;
            bfr[c2] = *(const bf16x8*)(B2 + (size_t)((ct * 4 + ks) * 64 + lane) * 8);
        }
        bf16x8 af[4];
#pragma unroll
        for (int rt = 0; rt < 4; ++rt)
            af[rt] = *(const bf16x8*)(As + (rt * 16 + tn) * LDA2 + k0);
#pragma unroll
        for (int rt = 0; rt < 4; ++rt)
#pragma unroll
            for (int c2 = 0; c2 < 2; ++c2)
                acc[rt][c2] = __builtin_amdgcn_mfma_f32_16x16x32_bf16(
                    af[rt], bfr[c2], acc[rt][c2], 0, 0, 0);
    }
#pragma unroll
    for (int c2 = 0; c2 < 2; ++c2) {
        int col = w * 32 + c2 * 16 + tn;
        float s = 0.f, s2 = 0.f;
#pragma unroll
        for (int rt = 0; rt < 4; ++rt)
#pragma unroll
            for (int r = 0; r < 4; ++r) {
                int row = rowb + rt * 16 + quad * 4 + r;
                float v = acc[rt][c2][r];
                mo[row * 128 + col] = f2bf(v);
                if (row < N) { s += v; s2 += v * v; }
            }
        s += __shfl_xor(s, 16);
        s += __shfl_xor(s, 32);
        s2 += __shfl_xor(s2, 16);
        s2 += __shfl_xor(s2, 32);
        if (quad == 0) {
            int slice = blockIdx.x & 63;
            atomicAdd(&statsl[(slice * 2 + 0) * 128 + col], s);
            atomicAdd(&statsl[(slice * 2 + 1) * 128 + col], s2);
        }
    }
}

// ---------------- BN finalize / pool / head ----------------

__global__ void k_bnfinal(const float* __restrict__ statsl, float* __restrict__ stats,
                          const float* __restrict__ gamma,
                          const float* __restrict__ beta, float n) {
    int j = threadIdx.x;
    if (j < HID) {
        float s = 0.f, s2 = 0.f;
        for (int sl = 0; sl < 64; ++sl) {
            s += statsl[(sl * 2 + 0) * 128 + j];
            s2 += statsl[(sl * 2 + 1) * 128 + j];
        }
        float mu = s / n;
        float var = s2 / n - mu * mu;
        float sc = gamma[j] * rsqrtf(var + BN_EPS);
        stats[256 + j] = sc;
        stats[384 + j] = beta[j] - mu * sc;
    }
}

// atomic-light pool: block = (graph, quarter), rows contiguous via gstart
__global__ __launch_bounds__(256) void k_pool(const ushort* __restrict__ y,
                                              const float* __restrict__ stats,
                                              const int* __restrict__ gstart,
                                              float* __restrict__ gsum) {
    int g = blockIdx.x >> 2, q = blockIdx.x & 3;
    int f = threadIdx.x & 127, half = threadIdx.x >> 7;
    int gs = gstart[g], ge = gstart[g + 1];
    int len = ge - gs;
    int r0 = gs + ((len * q) >> 2), r1 = gs + ((len * (q + 1)) >> 2);
    float sc = stats[256 + f], sh = stats[384 + f];
    float acc = 0.f;
    for (int n = r0 + half; n < r1; n += 2)
        acc += fmaxf(bf2f(y[n * HID + f]) * sc + sh, 0.f);
    __shared__ float ls[2][HID];
    ls[half][f] = acc;
    __syncthreads();
    if (half == 0) atomicAdd(&gsum[g * HID + f], ls[0][f] + ls[1][f]);
}

__global__ void k_head(const float* __restrict__ gsum, const int* __restrict__ gstart,
                       const float* __restrict__ w2, const float* __restrict__ b2,
                       float* __restrict__ out) {
    int g = blockIdx.x * blockDim.x + threadIdx.x;
    if (g >= NGRAPHS) return;
    float cnt = (float)(gstart[g + 1] - gstart[g]);
    float inv = 1.0f / fmaxf(cnt, 1.0f);
    float logits[NCLASSES];
    float mx = -1e30f;
    for (int c = 0; c < NCLASSES; ++c) {
        float acc = b2[c];
        for (int f = 0; f < HID; ++f) acc += gsum[g * HID + f] * inv * w2[c * HID + f];
        logits[c] = acc;
        mx = fmaxf(mx, acc);
    }
    float se = 0.f;
    for (int c = 0; c < NCLASSES; ++c) se += expf(logits[c] - mx);
    float lse = mx + logf(se);
    for (int c = 0; c < NCLASSES; ++c) out[g * NCLASSES + c] = logits[c] - lse;
}

// ---------------- launch ----------------

extern "C" void kernel_launch(void* const* d_in, const int* in_sizes, int n_in,
                              void* d_out, int out_size, void* d_ws, size_t ws_size,
                              hipStream_t stream) {
    const float* x     = (const float*)d_in[0];
    const int*   ei    = (const int*)d_in[1];
    const int*   batch = (const int*)d_in[2];
    const float* ggnnw = (const float*)d_in[3];
    const float* w_ih  = (const float*)d_in[4];
    const float* w_hh  = (const float*)d_in[5];
    const float* b_ih  = (const float*)d_in[6];
    const float* b_hh  = (const float*)d_in[7];
    const float* fc1_w = (const float*)d_in[8];
    // d_in[9] fc1_b: cancels exactly in training-mode BN -> unused
    const float* gamma = (const float*)d_in[10];
    const float* beta  = (const float*)d_in[11];
    const float* fc2_w = (const float*)d_in[12];
    const float* fc2_b = (const float*)d_in[13];
    float* out = (float*)d_out;

    const int N = in_sizes[0] / HID; // 100000
    const int E = in_sizes[1] / 2;   // 1600000
    const int nblk64 = (N + 63) / 64;
    const int P = nblk64 * 64;
    const int nbuck = (N + 511) >> 9; // 196

    char* w = (char*)d_ws;
    auto alloc = [&](size_t bytes) -> char* {
        char* p = w;
        w += (bytes + 255) & ~(size_t)255;
        return p;
    };
    ushort* A   = (ushort*)alloc(sizeof(ushort) * (size_t)P * 256); // [s | h] bf16
    ushort* y   = (ushort*)alloc(sizeof(ushort) * (size_t)P * HID); // fc1 output
    int2*   binned = (int2*)y; // alias: binned dead before k_mm writes y
    ushort* Bc2 = (ushort*)alloc(sizeof(ushort) * NLAYERS * 512 * 256);
    float*  C   = (float*)alloc(sizeof(float) * NLAYERS * 128 * 384);
    ushort* f1b = (ushort*)alloc(sizeof(ushort) * HID * HID);
    float*  bias = (float*)alloc(sizeof(float) * 512);
    int* rowstart = (int*)alloc(sizeof(int) * (N + 4));
    int* colb     = (int*)alloc(sizeof(int) * E);
    int* bstart   = (int*)alloc(sizeof(int) * (nbuck + 4));
    int* bcur     = (int*)alloc(sizeof(int) * (nbuck + 4));
    int* gstart   = (int*)alloc(sizeof(int) * (NGRAPHS + 4));
    // zero-initialized region: bhist, statsl (64 slices x 2 x 128), stats, gsum
    size_t zelems = (size_t)nbuck + 64 * 2 * 128 + 512 + NGRAPHS * HID;
    char* zbase = alloc(zelems * 4);
    int*   bhist  = (int*)zbase;
    float* statsl = (float*)(bhist + nbuck);
    float* stats  = statsl + 64 * 2 * 128;
    float* gsum   = stats + 512;

    hipMemsetAsync(zbase, 0, zelems * 4, stream);

    k_init_x<<<(N * HID + 255) / 256, 256, 0, stream>>>(x, A, N);
    k_wgemm<<<NLAYERS * 128, 128, 0, stream>>>(ggnnw, w_ih, C);
    k_build_Bc<<<(NLAYERS * 512 * 256 + 255) / 256, 256, 0, stream>>>(C, w_hh, Bc2);
    k_bias<<<1, 512, 0, stream>>>(b_ih, b_hh, bias);
    k_cvt_fc1<<<(16384 + 255) / 256, 256, 0, stream>>>(fc1_w, f1b);

    // staged CSR build (+ gstart fused into bhist dispatch)
    int nchunk = (E + CHUNK - 1) / CHUNK;
    int ngblk = (N + 256) / 256;
    k_bhist<<<nchunk + ngblk, 256, 0, stream>>>(ei, E, nbuck, bhist, batch, gstart, N,
                                                nchunk);
    k_bscan<<<1, 256, 0, stream>>>(bhist, nbuck, bstart, bcur, E);
    k_binfill<<<nchunk, 256, 0, stream>>>(ei, E, nbuck, bcur, binned);
    k_csr512<<<nbuck, 256, 0, stream>>>(binned, bstart, rowstart, colb, N, E);

    for (int l = 0; l < NLAYERS; ++l) {
        k_gather_bf<<<(N + 3) / 4, 256, 0, stream>>>(rowstart, colb, A, N);
        k_gru_mfma<<<nblk64, 256, 0, stream>>>(A, Bc2 + (size_t)l * 512 * 256,
                                               bias, A + 128);
    }

    // head: fc1 (+fused BN stats) -> BN finalize -> pool -> fc2 -> log_softmax
    k_mm_mfma<<<nblk64, 256, 0, stream>>>(A + 128, 256, f1b, y, statsl, N);
    k_bnfinal<<<1, 128, 0, stream>>>(statsl, stats, gamma, beta, (float)N);
    k_pool<<<NGRAPHS * 4, 256, 0, stream>>>(y, stats, gstart, gsum);
    k_head<<<1, 256, 0, stream>>>(gsum, gstart, fc2_w, fc2_b, out);
}

// Round 14
// 726.896 us; speedup vs baseline: 1.1794x; 1.0175x over previous
//
#include <hip/hip_runtime.h>
#include <math.h>

#define HID 128
#define NLAYERS 4
#define NGRAPHS 200
#define NCLASSES 10
#define BN_EPS 1e-5f

typedef short bf16x8 __attribute__((ext_vector_type(8)));
typedef float f32x4 __attribute__((ext_vector_type(4)));

__device__ __forceinline__ ushort f2bf(float f) {
    unsigned u = __float_as_uint(f);
    u = (u + 0x7fffu + ((u >> 16) & 1u)) >> 16;
    return (ushort)u;
}
__device__ __forceinline__ float bf2f(unsigned us) { return __uint_as_float(us << 16); }

// ---------------- prep kernels ----------------

// A[:,128:256] = bf16(x)  (h state lives only in A's h-half, bf16)
__global__ void k_init_x(const float* __restrict__ x, ushort* __restrict__ A, int N) {
    int idx = blockIdx.x * blockDim.x + threadIdx.x;
    if (idx < N * HID) {
        int n = idx >> 7, c = idx & 127;
        A[n * 256 + 128 + c] = f2bf(x[idx]);
    }
}

// C[l][k][j] = sum_o W_l[k][o] * w_ih[j][o]; blocks 0..3 also fold the bias vector.
__global__ __launch_bounds__(128) void k_wgemm(const float* __restrict__ W,
                                               const float* __restrict__ w_ih,
                                               const float* __restrict__ b_ih,
                                               const float* __restrict__ b_hh,
                                               float* __restrict__ C,
                                               float* __restrict__ bias) {
    int l = blockIdx.x >> 7, k = blockIdx.x & 127;
    __shared__ float wrow[128];
    wrow[threadIdx.x] = W[(l << 14) + k * 128 + threadIdx.x];
    __syncthreads();
    for (int j = threadIdx.x; j < 384; j += 128) {
        float acc = 0.f;
#pragma unroll 4
        for (int o = 0; o < 128; ++o) acc += wrow[o] * w_ih[j * 128 + o];
        C[((size_t)l * 128 + k) * 384 + j] = acc;
    }
    if (blockIdx.x < 4) {
        int j = blockIdx.x * 128 + threadIdx.x; // 0..511
        float v;
        if (j < 256)      v = b_ih[j] + b_hh[j];
        else if (j < 384) v = b_ih[j];
        else              v = b_hh[j - 128];
        bias[j] = v;
    }
}

// Per-layer combined GRU weights in MFMA-fragment order (K=256 over [s|h], 512 outs)
__global__ void k_build_Bc(const float* __restrict__ C, const float* __restrict__ w_hh,
                           ushort* __restrict__ Bc2) {
    int idx = blockIdx.x * blockDim.x + threadIdx.x;
    if (idx >= NLAYERS * 512 * 256) return;
    int jf = idx & 7, lane = (idx >> 3) & 63, ks = (idx >> 9) & 7, ct = (idx >> 12) & 31;
    int l = idx >> 17;
    int o = ct * 16 + (lane & 15);
    int k = ks * 32 + (lane >> 4) * 8 + jf;
    float v;
    if (k < 128)      v = (o < 384) ? C[((size_t)l * 128 + k) * 384 + o] : 0.f;
    else if (o < 256) v = w_hh[o * 128 + (k - 128)];
    else if (o < 384) v = 0.f;
    else              v = w_hh[(o - 128) * 128 + (k - 128)];
    Bc2[idx] = f2bf(v);
}

// fc1_w[o][k] -> fragment order (K=128: ks in [0,4), ct in [0,8))
__global__ void k_cvt_fc1(const float* __restrict__ w, ushort* __restrict__ B2) {
    int idx = blockIdx.x * blockDim.x + threadIdx.x;
    if (idx >= 16384) return;
    int j = idx & 7, lane = (idx >> 3) & 63, ks = (idx >> 9) & 3, ct = idx >> 11;
    int o = ct * 16 + (lane & 15);
    int k = ks * 32 + (lane >> 4) * 8 + j;
    B2[idx] = f2bf(w[o * 128 + k]);
}

// ---------------- CSR build: staged counting-sort (no write amplification) ----------
// R10 lesson: NO dynamically-indexed register arrays (-> scratch). Scatter pass
// re-reads the chunk from global (L1/L2-hot after the hist pass).

#define CHUNK 2048

// blocks [0,nchunk): per-chunk bucket histogram; blocks [nchunk, ...): gstart
__global__ __launch_bounds__(256) void k_bhist(const int* __restrict__ ei, int E,
                                               int nb, int* __restrict__ bhist,
                                               const int* __restrict__ batch,
                                               int* __restrict__ gstart, int N,
                                               int nchunk) {
    if ((int)blockIdx.x < nchunk) {
        __shared__ int lh[256];
        int t = threadIdx.x;
        lh[t] = 0;
        __syncthreads();
        int base = blockIdx.x * CHUNK;
        int end = min(base + CHUNK, E);
        for (int i = base + t; i < end; i += 256) atomicAdd(&lh[ei[E + i] >> 9], 1);
        __syncthreads();
        if (t < nb && lh[t]) atomicAdd(&bhist[t], lh[t]);
    } else {
        int n = (blockIdx.x - nchunk) * 256 + threadIdx.x;
        if (n > N) return;
        int curb = (n == N) ? NGRAPHS : batch[n];
        int prev = (n == 0) ? -1 : batch[n - 1];
        for (int g = prev + 1; g <= curb; ++g) gstart[g] = n;
    }
}

__global__ void k_bscan(const int* __restrict__ bhist, int nb, int* __restrict__ bstart,
                        int* __restrict__ bcur, int E) {
    __shared__ int s[256];
    int t = threadIdx.x;
    int v = (t < nb) ? bhist[t] : 0;
    s[t] = v;
    __syncthreads();
    for (int off = 1; off < 256; off <<= 1) {
        int a = (t >= off) ? s[t - off] : 0;
        __syncthreads();
        s[t] += a;
        __syncthreads();
    }
    if (t < nb) { int ex = s[t] - v; bstart[t] = ex; bcur[t] = ex; }
    if (t == 0) bstart[nb] = E;
}

__global__ __launch_bounds__(256) void k_binfill(const int* __restrict__ ei, int E,
                                                 int nb, int* __restrict__ bcur,
                                                 int2* __restrict__ binned) {
    __shared__ int eh[256], eoff[256], ecur[256], gbase[256];
    __shared__ int2 sbuf[CHUNK];
    int t = threadIdx.x;
    eh[t] = 0; ecur[t] = 0;
    __syncthreads();
    int base = blockIdx.x * CHUNK;
    int cnt = min(CHUNK, E - base);
    for (int i = t; i < cnt; i += 256) atomicAdd(&eh[ei[E + base + i] >> 9], 1);
    __syncthreads();
    int v = eh[t];
    eoff[t] = v;
    __syncthreads();
    for (int off = 1; off < 256; off <<= 1) {
        int a = (t >= off) ? eoff[t - off] : 0;
        __syncthreads();
        eoff[t] += a;
        __syncthreads();
    }
    int excl = eoff[t] - v;
    __syncthreads();
    eoff[t] = excl;
    __syncthreads();
    for (int i = t; i < cnt; i += 256) {
        int s = ei[base + i], d = ei[E + base + i];
        int b = d >> 9;
        int slot = eoff[b] + atomicAdd(&ecur[b], 1);
        sbuf[slot] = make_int2(s, d);
    }
    __syncthreads();
    if (t < nb && eh[t]) gbase[t] = atomicAdd(&bcur[t], eh[t]);
    __syncthreads();
    for (int i = t; i < cnt; i += 256) {
        int2 e = sbuf[i];
        int b = e.y >> 9;
        binned[gbase[b] + (i - eoff[b])] = e;
    }
}

__global__ __launch_bounds__(256) void k_csr512(const int2* __restrict__ binned,
                                                const int* __restrict__ bstart,
                                                int* __restrict__ rowstart,
                                                int* __restrict__ col, int N, int E) {
    __shared__ int h[512], cur[512], sc[512];
    int t = threadIdx.x, b = blockIdx.x;
    int es = bstart[b], ee = bstart[b + 1];
    for (int i = t; i < 512; i += 256) h[i] = 0;
    __syncthreads();
    for (int i = es + t; i < ee; i += 256) atomicAdd(&h[binned[i].y & 511], 1);
    __syncthreads();
    for (int i = t; i < 512; i += 256) sc[i] = h[i];
    __syncthreads();
    for (int off = 1; off < 512; off <<= 1) {
        int i0 = t, i1 = t + 256;
        int a0 = (i0 >= off) ? sc[i0 - off] : 0;
        int a1 = (i1 >= off) ? sc[i1 - off] : 0;
        __syncthreads();
        sc[i0] += a0; sc[i1] += a1;
        __syncthreads();
    }
    for (int i = t; i < 512; i += 256) {
        int excl = sc[i] - h[i];
        cur[i] = excl;
        int node = (b << 9) + i;
        if (node < N) rowstart[node] = es + excl;
    }
    __syncthreads();
    for (int i = es + t; i < ee; i += 256) {
        int2 e = binned[i];
        int p = atomicAdd(&cur[e.y & 511], 1);
        col[es + p] = e.x;
    }
    if (b == 0 && t == 0) rowstart[N] = E;
}

// ---------------- CSR gather: A[:,0:128] = sum over in-edges of A[src,128:256] --------
// TLP is the latency hiding (R12: deeper row-unroll raised VGPR 28->44, occupancy
// 68->44%, 60->92 us — reverted). R14: software-pipeline the col-index loads one
// iteration ahead (+4 VGPR) to break the col->row dependent-load chain.

__global__ __launch_bounds__(256) void k_gather_bf(const int* __restrict__ rowstart,
                                                   const int* __restrict__ col,
                                                   ushort* __restrict__ A, int N) {
    int node = blockIdx.x * 4 + (threadIdx.x >> 6);
    int lane = threadIdx.x & 63;
    if (node >= N) return;
    int s = rowstart[node], e = rowstart[node + 1];
    int sub = lane >> 4;   // edge slot 0..3
    int chunk = lane & 15; // 16B chunk in row
    const ushort* hb = A + 128; // h-half, stride 256
    float acc[8];
#pragma unroll
    for (int k = 0; k < 8; ++k) acc[k] = 0.f;
    int i = s + sub;
    if (i + 12 < e) {
        int c0 = col[i], c1 = col[i + 4], c2 = col[i + 8], c3 = col[i + 12];
        while (true) {
            int j = i + 16;
            bool more = (j + 12 < e);
            int n0 = 0, n1 = 0, n2 = 0, n3 = 0;
            if (more) { n0 = col[j]; n1 = col[j + 4]; n2 = col[j + 8]; n3 = col[j + 12]; }
            bf16x8 v0 = *(const bf16x8*)(hb + (size_t)c0 * 256 + chunk * 8);
            bf16x8 v1 = *(const bf16x8*)(hb + (size_t)c1 * 256 + chunk * 8);
            bf16x8 v2 = *(const bf16x8*)(hb + (size_t)c2 * 256 + chunk * 8);
            bf16x8 v3 = *(const bf16x8*)(hb + (size_t)c3 * 256 + chunk * 8);
#pragma unroll
            for (int k = 0; k < 8; ++k) {
                acc[k] += bf2f((ushort)v0[k]) + bf2f((ushort)v1[k]);
                acc[k] += bf2f((ushort)v2[k]) + bf2f((ushort)v3[k]);
            }
            i = j;
            if (!more) break;
            c0 = n0; c1 = n1; c2 = n2; c3 = n3;
        }
    }
    for (; i < e; i += 4) {
        int c0 = col[i];
        bf16x8 v0 = *(const bf16x8*)(hb + (size_t)c0 * 256 + chunk * 8);
#pragma unroll
        for (int k = 0; k < 8; ++k) acc[k] += bf2f((ushort)v0[k]);
    }
#pragma unroll
    for (int k = 0; k < 8; ++k) {
        acc[k] += __shfl_xor(acc[k], 16);
        acc[k] += __shfl_xor(acc[k], 32);
    }
    if (sub == 0) {
        union { ushort u[8]; bf16x8 v; } o;
#pragma unroll
        for (int k = 0; k < 8; ++k) o.u[k] = f2bf(acc[k]);
        *(bf16x8*)(A + (size_t)node * 256 + chunk * 8) = o.v;
    }
}

// ---------------- fused GRU GEMM (K=256 over [s|h]); h state bf16-only --------------
// NOTE: min-waves MUST stay 2 — at 4 the allocator caps VGPR at 64 and spills the
// 128-reg accumulator array to scratch (R8: 1.3 GB HBM traffic, 274 us).

#define LDA 264
__global__ __launch_bounds__(256, 2) void k_gru_mfma(
    const ushort* __restrict__ A, const ushort* __restrict__ Bc2,
    const float* __restrict__ bias, ushort* __restrict__ Ah) {
    __shared__ ushort As[64 * LDA];
    int t = threadIdx.x;
    int rowb = blockIdx.x << 6;
    for (int c = t; c < 2048; c += 256) {
        int r = c >> 5, off = (c & 31) * 8;
        *(bf16x8*)(As + r * LDA + off) =
            *(const bf16x8*)(A + (size_t)(rowb + r) * 256 + off);
    }
    __syncthreads();
    int w = t >> 6, lane = t & 63;
    int quad = lane >> 4, tn = lane & 15;
    f32x4 acc[4][4][2];
#pragma unroll
    for (int rt = 0; rt < 4; ++rt)
#pragma unroll
        for (int g = 0; g < 4; ++g)
#pragma unroll
            for (int c2 = 0; c2 < 2; ++c2) acc[rt][g][c2] = (f32x4){0.f, 0.f, 0.f, 0.f};
    for (int ks = 0; ks < 8; ++ks) {
        int k0 = ks * 32 + quad * 8;
        bf16x8 bfr[4][2];
#pragma unroll
        for (int g = 0; g < 4; ++g)
#pragma unroll
            for (int c2 = 0; c2 < 2; ++c2) {
                int ct = g * 8 + w * 2 + c2;
                bfr[g][c2] = *(const bf16x8*)(Bc2 + (size_t)((ct * 8 + ks) * 64 + lane) * 8);
            }
        bf16x8 af[4];
#pragma unroll
        for (int rt = 0; rt < 4; ++rt)
            af[rt] = *(const bf16x8*)(As + (rt * 16 + tn) * LDA + k0);
#pragma unroll
        for (int rt = 0; rt < 4; ++rt)
#pragma unroll
            for (int g = 0; g < 4; ++g)
#pragma unroll
                for (int c2 = 0; c2 < 2; ++c2)
                    acc[rt][g][c2] = __builtin_amdgcn_mfma_f32_16x16x32_bf16(
                        af[rt], bfr[g][c2], acc[rt][g][c2], 0, 0, 0);
    }
#pragma unroll
    for (int c2 = 0; c2 < 2; ++c2) {
        int cc = w * 32 + c2 * 16 + tn;
        float br = bias[cc], bz = bias[128 + cc], bin = bias[256 + cc], bhn = bias[384 + cc];
#pragma unroll
        for (int rt = 0; rt < 4; ++rt)
#pragma unroll
            for (int r = 0; r < 4; ++r) {
                int rl = rt * 16 + quad * 4 + r;
                int row = rowb + rl;
                float ur = acc[rt][0][c2][r] + br;
                float uz = acc[rt][1][c2][r] + bz;
                float xin = acc[rt][2][c2][r] + bin;
                float xhn = acc[rt][3][c2][r] + bhn;
                float rr = 1.f / (1.f + __expf(-ur));
                float zz = 1.f / (1.f + __expf(-uz));
                float xt = xin + rr * xhn;
                float ex = __expf(2.f * fminf(fmaxf(xt, -15.f), 15.f));
                float nn = (ex - 1.f) / (ex + 1.f);
                float ho = bf2f(As[rl * LDA + 128 + cc]);
                float hv = (1.f - zz) * nn + zz * ho;
                Ah[(size_t)row * 256 + cc] = f2bf(hv);
            }
    }
}

// ---------------- MFMA GEMM (fc1) with fused BN-stats ----------

#define LDA2 136
__global__ __launch_bounds__(256, 2) void k_mm_mfma(
    const ushort* __restrict__ Ain, int astride, const ushort* __restrict__ B2,
    ushort* __restrict__ mo, float* __restrict__ statsl, int N) {
    __shared__ ushort As[64 * LDA2];
    int t = threadIdx.x;
    int rowb = blockIdx.x << 6;
    for (int c = t; c < 1024; c += 256) {
        int r = c >> 4, off = (c & 15) * 8;
        *(bf16x8*)(As + r * LDA2 + off) =
            *(const bf16x8*)(Ain + (size_t)(rowb + r) * astride + off);
    }
    __syncthreads();
    int w = t >> 6, lane = t & 63;
    int quad = lane >> 4, tn = lane & 15;
    f32x4 acc[4][2];
#pragma unroll
    for (int rt = 0; rt < 4; ++rt)
#pragma unroll
        for (int c2 = 0; c2 < 2; ++c2) acc[rt][c2] = (f32x4){0.f, 0.f, 0.f, 0.f};
    for (int ks = 0; ks < 4; ++ks) {
        int k0 = ks * 32 + quad * 8;
        bf16x8 bfr[2];
#pragma unroll
        for (int c2 = 0; c2 < 2; ++c2) {
            int ct = w * 2 + c2;
            bfr[c2] = *(const bf16x8*)(B2 + (size_t)((ct * 4 + ks) * 64 + lane) * 8);
        }
        bf16x8 af[4];
#pragma unroll
        for (int rt = 0; rt < 4; ++rt)
            af[rt] = *(const bf16x8*)(As + (rt * 16 + tn) * LDA2 + k0);
#pragma unroll
        for (int rt = 0; rt < 4; ++rt)
#pragma unroll
            for (int c2 = 0; c2 < 2; ++c2)
                acc[rt][c2] = __builtin_amdgcn_mfma_f32_16x16x32_bf16(
                    af[rt], bfr[c2], acc[rt][c2], 0, 0, 0);
    }
#pragma unroll
    for (int c2 = 0; c2 < 2; ++c2) {
        int col = w * 32 + c2 * 16 + tn;
        float s = 0.f, s2 = 0.f;
#pragma unroll
        for (int rt = 0; rt < 4; ++rt)
#pragma unroll
            for (int r = 0; r < 4; ++r) {
                int row = rowb + rt * 16 + quad * 4 + r;
                float v = acc[rt][c2][r];
                mo[row * 128 + col] = f2bf(v);
                if (row < N) { s += v; s2 += v * v; }
            }
        s += __shfl_xor(s, 16);
        s += __shfl_xor(s, 32);
        s2 += __shfl_xor(s2, 16);
        s2 += __shfl_xor(s2, 32);
        if (quad == 0) {
            int slice = blockIdx.x & 63;
            atomicAdd(&statsl[(slice * 2 + 0) * 128 + col], s);
            atomicAdd(&statsl[(slice * 2 + 1) * 128 + col], s2);
        }
    }
}

// ---------------- BN finalize / pool / head ----------------

__global__ void k_bnfinal(const float* __restrict__ statsl, float* __restrict__ stats,
                          const float* __restrict__ gamma,
                          const float* __restrict__ beta, float n) {
    int j = threadIdx.x;
    if (j < HID) {
        float s = 0.f, s2 = 0.f;
        for (int sl = 0; sl < 64; ++sl) {
            s += statsl[(sl * 2 + 0) * 128 + j];
            s2 += statsl[(sl * 2 + 1) * 128 + j];
        }
        float mu = s / n;
        float var = s2 / n - mu * mu;
        float sc = gamma[j] * rsqrtf(var + BN_EPS);
        stats[256 + j] = sc;
        stats[384 + j] = beta[j] - mu * sc;
    }
}

// atomic-light pool: block = (graph, quarter), rows contiguous via gstart
__global__ __launch_bounds__(256) void k_pool(const ushort* __restrict__ y,
                                              const float* __restrict__ stats,
                                              const int* __restrict__ gstart,
                                              float* __restrict__ gsum) {
    int g = blockIdx.x >> 2, q = blockIdx.x & 3;
    int f = threadIdx.x & 127, half = threadIdx.x >> 7;
    int gs = gstart[g], ge = gstart[g + 1];
    int len = ge - gs;
    int r0 = gs + ((len * q) >> 2), r1 = gs + ((len * (q + 1)) >> 2);
    float sc = stats[256 + f], sh = stats[384 + f];
    float acc = 0.f;
    for (int n = r0 + half; n < r1; n += 2)
        acc += fmaxf(bf2f(y[n * HID + f]) * sc + sh, 0.f);
    __shared__ float ls[2][HID];
    ls[half][f] = acc;
    __syncthreads();
    if (half == 0) atomicAdd(&gsum[g * HID + f], ls[0][f] + ls[1][f]);
}

__global__ void k_head(const float* __restrict__ gsum, const int* __restrict__ gstart,
                       const float* __restrict__ w2, const float* __restrict__ b2,
                       float* __restrict__ out) {
    int g = blockIdx.x * blockDim.x + threadIdx.x;
    if (g >= NGRAPHS) return;
    float cnt = (float)(gstart[g + 1] - gstart[g]);
    float inv = 1.0f / fmaxf(cnt, 1.0f);
    float logits[NCLASSES];
    float mx = -1e30f;
    for (int c = 0; c < NCLASSES; ++c) {
        float acc = b2[c];
        for (int f = 0; f < HID; ++f) acc += gsum[g * HID + f] * inv * w2[c * HID + f];
        logits[c] = acc;
        mx = fmaxf(mx, acc);
    }
    float se = 0.f;
    for (int c = 0; c < NCLASSES; ++c) se += expf(logits[c] - mx);
    float lse = mx + logf(se);
    for (int c = 0; c < NCLASSES; ++c) out[g * NCLASSES + c] = logits[c] - lse;
}

// ---------------- launch ----------------

extern "C" void kernel_launch(void* const* d_in, const int* in_sizes, int n_in,
                              void* d_out, int out_size, void* d_ws, size_t ws_size,
                              hipStream_t stream) {
    const float* x     = (const float*)d_in[0];
    const int*   ei    = (const int*)d_in[1];
    const int*   batch = (const int*)d_in[2];
    const float* ggnnw = (const float*)d_in[3];
    const float* w_ih  = (const float*)d_in[4];
    const float* w_hh  = (const float*)d_in[5];
    const float* b_ih  = (const float*)d_in[6];
    const float* b_hh  = (const float*)d_in[7];
    const float* fc1_w = (const float*)d_in[8];
    // d_in[9] fc1_b: cancels exactly in training-mode BN -> unused
    const float* gamma = (const float*)d_in[10];
    const float* beta  = (const float*)d_in[11];
    const float* fc2_w = (const float*)d_in[12];
    const float* fc2_b = (const float*)d_in[13];
    float* out = (float*)d_out;

    const int N = in_sizes[0] / HID; // 100000
    const int E = in_sizes[1] / 2;   // 1600000
    const int nblk64 = (N + 63) / 64;
    const int P = nblk64 * 64;
    const int nbuck = (N + 511) >> 9; // 196

    char* w = (char*)d_ws;
    auto alloc = [&](size_t bytes) -> char* {
        char* p = w;
        w += (bytes + 255) & ~(size_t)255;
        return p;
    };
    ushort* A   = (ushort*)alloc(sizeof(ushort) * (size_t)P * 256); // [s | h] bf16
    ushort* y   = (ushort*)alloc(sizeof(ushort) * (size_t)P * HID); // fc1 output
    int2*   binned = (int2*)y; // alias: binned dead before k_mm writes y
    ushort* Bc2 = (ushort*)alloc(sizeof(ushort) * NLAYERS * 512 * 256);
    float*  C   = (float*)alloc(sizeof(float) * NLAYERS * 128 * 384);
    ushort* f1b = (ushort*)alloc(sizeof(ushort) * HID * HID);
    float*  bias = (float*)alloc(sizeof(float) * 512);
    int* rowstart = (int*)alloc(sizeof(int) * (N + 4));
    int* colb     = (int*)alloc(sizeof(int) * E);
    int* bstart   = (int*)alloc(sizeof(int) * (nbuck + 4));
    int* bcur     = (int*)alloc(sizeof(int) * (nbuck + 4));
    int* gstart   = (int*)alloc(sizeof(int) * (NGRAPHS + 4));
    // zero-initialized region: bhist, statsl (64 slices x 2 x 128), stats, gsum
    size_t zelems = (size_t)nbuck + 64 * 2 * 128 + 512 + NGRAPHS * HID;
    char* zbase = alloc(zelems * 4);
    int*   bhist  = (int*)zbase;
    float* statsl = (float*)(bhist + nbuck);
    float* stats  = statsl + 64 * 2 * 128;
    float* gsum   = stats + 512;

    hipMemsetAsync(zbase, 0, zelems * 4, stream);

    k_init_x<<<(N * HID + 255) / 256, 256, 0, stream>>>(x, A, N);
    k_wgemm<<<NLAYERS * 128, 128, 0, stream>>>(ggnnw, w_ih, b_ih, b_hh, C, bias);
    k_build_Bc<<<(NLAYERS * 512 * 256 + 255) / 256, 256, 0, stream>>>(C, w_hh, Bc2);
    k_cvt_fc1<<<(16384 + 255) / 256, 256, 0, stream>>>(fc1_w, f1b);

    // staged CSR build (+ gstart fused into bhist dispatch)
    int nchunk = (E + CHUNK - 1) / CHUNK;
    int ngblk = (N + 256) / 256;
    k_bhist<<<nchunk + ngblk, 256, 0, stream>>>(ei, E, nbuck, bhist, batch, gstart, N,
                                                nchunk);
    k_bscan<<<1, 256, 0, stream>>>(bhist, nbuck, bstart, bcur, E);
    k_binfill<<<nchunk, 256, 0, stream>>>(ei, E, nbuck, bcur, binned);
    k_csr512<<<nbuck, 256, 0, stream>>>(binned, bstart, rowstart, colb, N, E);

    for (int l = 0; l < NLAYERS; ++l) {
        k_gather_bf<<<(N + 3) / 4, 256, 0, stream>>>(rowstart, colb, A, N);
        k_gru_mfma<<<nblk64, 256, 0, stream>>>(A, Bc2 + (size_t)l * 512 * 256,
                                               bias, A + 128);
    }

    // head: fc1 (+fused BN stats) -> BN finalize -> pool -> fc2 -> log_softmax
    k_mm_mfma<<<nblk64, 256, 0, stream>>>(A + 128, 256, f1b, y, statsl, N);
    k_bnfinal<<<1, 128, 0, stream>>>(statsl, stats, gamma, beta, (float)N);
    k_pool<<<NGRAPHS * 4, 256, 0, stream>>>(y, stats, gstart, gsum);
    k_head<<<1, 256, 0, stream>>>(gsum, gstart, fc2_w, fc2_b, out);
}